// Round 7
// baseline (1227.398 us; speedup 1.0000x reference)
//
#include <hip/hip_runtime.h>

// Problem constants (fixed by the reference setup_inputs()).
#define KK 27
#define PP 100000
#define C_IN 32
#define C_OUT 32
#define N_IN 200000
#define N_OUT 400000

// Output-slice locality parameters.
#define SLICES 16
#define ROWS_PER_SLICE (N_OUT / SLICES)    // 25000 rows -> 3.2 MB, fits 4 MB XCD L2
#define XCDS 8
#define CHUNK 4000                          // pairs scanned per block
#define CGRPS (PP / CHUNK)                  // 25
#define HALF_BLOCKS (XCDS * CGRPS * KK)     // 8*25*27 = 5400
#define TOTAL_BLOCKS (2 * HALF_BLOCKS)      // 10800

// Native clang vector types — required by __builtin_nontemporal_load
// (HIP_vector_type structs like int4/float4 are rejected).
typedef int   vint4   __attribute__((ext_vector_type(4)));
typedef float vfloat4 __attribute__((ext_vector_type(4)));

// ---------------------------------------------------------------------------
// Kernel 1: out[n][c] = bias[c]  (float4-vectorized broadcast init)
// ---------------------------------------------------------------------------
__global__ __launch_bounds__(256) void init_out_kernel(
    vfloat4* __restrict__ out4, const vfloat4* __restrict__ bias4) {
    int i = blockIdx.x * 256 + threadIdx.x;        // float4 index
    out4[i] = bias4[i & 7];
}

// ---------------------------------------------------------------------------
// Kernel 2: slice-filtered rulebook scatter.
//   Linear grid decode (blockIdx.x = b):
//     sub   = b / HALF_BLOCKS      temporal half: slices 0-7 then 8-15
//     xslc  = (b % HALF_BLOCKS) % 8     -> XCD-affine slice (blockIdx%8 ~ XCD)
//     cgrp  = ((b % HALF_BLOCKS) / 8) % 25   -> which 4000-pair chunk
//     k     = ((b % HALF_BLOCKS) / 8) / 25   -> kernel offset
//   Each 32-lane group scans a contiguous 500-pair span with int4 loads and
//   does gather+FMA+atomic only for pairs whose pout is in this block's slice.
//   Match predicate is group-uniform (no lane divergence within a group).
// ---------------------------------------------------------------------------
__global__ __launch_bounds__(256) void spconv_sliced_kernel(
    const float* __restrict__ feats,      // [N_IN, 32]
    const float* __restrict__ weight,     // [K, 32, 32]
    const int* __restrict__ pin,          // [K, P] int32
    const int* __restrict__ pout,         // [K, P] int32
    float* __restrict__ out)              // [N_OUT, 32]
{
    const int b    = blockIdx.x;
    const int sub  = b / HALF_BLOCKS;          // 0 or 1
    const int bb   = b % HALF_BLOCKS;
    const int xslc = bb % XCDS;
    const int rest = bb / XCDS;                // 0..674
    const int cgrp = rest % CGRPS;             // 0..24
    const int k    = rest / CGRPS;             // 0..26
    const int r_lo = (xslc + XCDS * sub) * ROWS_PER_SLICE;

    const int c   = threadIdx.x & 31;
    const int grp = threadIdx.x >> 5;

    // Weight column W[k][:, c] in registers (k is block-uniform; 27 KB of
    // weights stays L1/L2 resident across the 10800 blocks).
    const float* w = weight + k * (C_IN * C_OUT) + c;
    float wcol[C_IN];
#pragma unroll
    for (int ci = 0; ci < C_IN; ++ci) wcol[ci] = w[ci * C_OUT];

    const int* pin_k  = pin  + k * PP;
    const int* pout_k = pout + k * PP;

    // Each group owns a contiguous 500-pair span of this block's 4000-pair
    // chunk; scan it 4 indices at a time (int4, non-temporal).
    const int span = cgrp * CHUNK + grp * (CHUNK / 8);
    const vint4* po4p = (const vint4*)(pout_k + span);

    for (int i4 = 0; i4 < CHUNK / 8 / 4; ++i4) {   // 125 iterations
        const vint4 po4 = __builtin_nontemporal_load(po4p + i4);
#pragma unroll
        for (int j = 0; j < 4; ++j) {
            const int io = po4[j];
            if ((unsigned)(io - r_lo) < (unsigned)ROWS_PER_SLICE) {
                const int p  = span + i4 * 4 + j;
                const int ii = __builtin_nontemporal_load(pin_k + p);

                const vfloat4* f4 = (const vfloat4*)(feats + ii * 32);
                float acc = 0.0f;
#pragma unroll
                for (int q = 0; q < 8; ++q) {
                    const vfloat4 f = __builtin_nontemporal_load(f4 + q);
                    acc = fmaf(f.x, wcol[4 * q + 0], acc);
                    acc = fmaf(f.y, wcol[4 * q + 1], acc);
                    acc = fmaf(f.z, wcol[4 * q + 2], acc);
                    acc = fmaf(f.w, wcol[4 * q + 3], acc);
                }
                // HW global_atomic_add_f32 (device scope); "unsafe" = denorm
                // flushing semantics, fine here.
                unsafeAtomicAdd(out + io * 32 + c, acc);
            }
        }
    }
}

// ---------------------------------------------------------------------------
// Launch
// ---------------------------------------------------------------------------
extern "C" void kernel_launch(void* const* d_in, const int* in_sizes, int n_in,
                              void* d_out, int out_size, void* d_ws, size_t ws_size,
                              hipStream_t stream) {
    const float* feats  = (const float*)d_in[0];       // [N_IN, 32]
    const float* weight = (const float*)d_in[1];       // [K, 32, 32]
    const float* bias   = (const float*)d_in[2];       // [32]
    const int*   pin    = (const int*)d_in[3];         // [K, P] int32
    const int*   pout   = (const int*)d_in[4];         // [K, P] int32
    float*       out    = (float*)d_out;               // [N_OUT, 32]

    // 1) out = bias (clears the 0xAA poison)
    const int n_f4 = N_OUT * C_OUT / 4;                // 3,200,000
    init_out_kernel<<<n_f4 / 256, 256, 0, stream>>>(
        (vfloat4*)out, (const vfloat4*)bias);

    // 2) slice-filtered gather-GEMM-scatter
    spconv_sliced_kernel<<<TOTAL_BLOCKS, 256, 0, stream>>>(
        feats, weight, pin, pout, out);
}